// Round 1
// baseline (626.486 us; speedup 1.0000x reference)
//
#include <hip/hip_runtime.h>
#include <hip/hip_bf16.h>
#include <math.h>

#define B_ 64
#define P_ 128
#define C_ 72
#define TI 16            // i-rows per block
#define NJG 16           // j-groups (threads per i-row)
#define JPT (P_ / NJG)   // j's per thread = 8
#define BLK (TI * NJG)   // 256 threads
#define CH 8             // reduction chunk

__device__ __forceinline__ float psi_f(float v) {
    return copysignf(log1pf(fabsf(v)), v);
}

// ---------------- Kernel 1: per-node precompute -------------------------
// A[n][c]  = sum_k h[n][k] * We1[k][c]
// Bc[n][c] = sum_k h[n][k] * We1[72+k][c] + be1[c]
__global__ __launch_bounds__(192) void pre_kernel(
    const float* __restrict__ h, const float* __restrict__ We1,
    const float* __restrict__ be1, float* __restrict__ A, float* __restrict__ Bc)
{
    int n = blockIdx.x;
    int t = threadIdx.x;
    __shared__ float h_s[C_];
    if (t < C_) h_s[t] = h[n * C_ + t];
    __syncthreads();
    if (t < C_) {
        float acc = 0.f;
        #pragma unroll 8
        for (int k = 0; k < C_; ++k) acc = fmaf(h_s[k], We1[k * C_ + t], acc);
        A[n * C_ + t] = acc;
    } else if (t < 2 * C_) {
        int c = t - C_;
        float acc = be1[c];
        #pragma unroll 8
        for (int k = 0; k < C_; ++k) acc = fmaf(h_s[k], We1[(C_ + k) * C_ + c], acc);
        Bc[n * C_ + c] = acc;
    }
}

// ---------------- Kernel 2: edge MLP + weighted aggregation -------------
__global__ __launch_bounds__(BLK, 2) void edge_kernel(
    const float* __restrict__ x, const float* __restrict__ A,
    const float* __restrict__ Bc, const float* __restrict__ We1,
    const float* __restrict__ We2, const float* __restrict__ be2,
    const float* __restrict__ Wm, const float* __restrict__ bm,
    const float* __restrict__ Wx,
    float* __restrict__ wm_out, float* __restrict__ xacc_out)
{
    __shared__ float A_s[TI][C_ + 1];       // pad -> stride 73, conflict-free
    __shared__ float Bc_s[P_][C_ + 1];
    __shared__ float xj_s[P_][4];
    __shared__ float w144_s[C_], w145_s[C_], be2_s[C_], Wm_s[C_], Wx_s[C_];
    __shared__ float red_s[BLK][CH + 1];

    int b  = blockIdx.x / (P_ / TI);
    int it = blockIdx.x - b * (P_ / TI);
    int t  = threadIdx.x;
    int li = t & (TI - 1);
    int jg = t >> 4;          // 0..15
    int i  = it * TI + li;
    int node_i = b * P_ + i;

    for (int idx = t; idx < TI * C_; idx += BLK) {
        int r = idx / C_, c = idx - r * C_;
        A_s[r][c] = A[(b * P_ + it * TI + r) * C_ + c];
    }
    for (int idx = t; idx < P_ * C_; idx += BLK) {
        int r = idx / C_, c = idx - r * C_;
        Bc_s[r][c] = Bc[(b * P_ + r) * C_ + c];
    }
    for (int idx = t; idx < P_ * 4; idx += BLK)
        xj_s[idx >> 2][idx & 3] = x[b * P_ * 4 + idx];
    if (t < C_) {
        w144_s[t] = We1[144 * C_ + t];
        w145_s[t] = We1[145 * C_ + t];
        be2_s[t]  = be2[t];
        Wm_s[t]   = Wm[t];
        Wx_s[t]   = Wx[t];
    }
    __syncthreads();

    float xi0 = xj_s[i][0], xi1 = xj_s[i][1], xi2 = xj_s[i][2], xi3 = xj_s[i][3];
    float bm0 = bm[0];

    float wm_p[C_];
    #pragma unroll
    for (int c = 0; c < C_; ++c) wm_p[c] = 0.f;
    float xa0 = 0.f, xa1 = 0.f, xa2 = 0.f, xa3 = 0.f;

    for (int jj = 0; jj < JPT; ++jj) {
        int j = jg * JPT + jj;
        float xj0 = xj_s[j][0], xj1 = xj_s[j][1], xj2 = xj_s[j][2], xj3 = xj_s[j][3];
        float d0 = xi0 - xj0, d1 = xi1 - xj1, d2 = xi2 - xj2, d3 = xi3 - xj3;
        float nn = d0 * d0 - d1 * d1 - d2 * d2 - d3 * d3;
        float pp = xi0 * xj0 - xi1 * xj1 - xi2 * xj2 - xi3 * xj3;
        float n_ = psi_f(nn);
        float p_ = psi_f(pp);

        float m2[C_];
        #pragma unroll
        for (int c = 0; c < C_; ++c) m2[c] = be2_s[c];

        // m2 += relu(A_i + Bc_j + n*w144 + p*w145)[k] * We2[k][:]
        #pragma unroll 2
        for (int k = 0; k < C_; ++k) {
            float v = A_s[li][k] + Bc_s[j][k];
            v = fmaf(n_, w144_s[k], v);
            v = fmaf(p_, w145_s[k], v);
            v = fmaxf(v, 0.f);
            const float4* w4 = reinterpret_cast<const float4*>(We2 + k * C_);
            #pragma unroll
            for (int c4 = 0; c4 < C_ / 4; ++c4) {
                float4 wv = w4[c4];
                m2[4 * c4 + 0] = fmaf(v, wv.x, m2[4 * c4 + 0]);
                m2[4 * c4 + 1] = fmaf(v, wv.y, m2[4 * c4 + 1]);
                m2[4 * c4 + 2] = fmaf(v, wv.z, m2[4 * c4 + 2]);
                m2[4 * c4 + 3] = fmaf(v, wv.w, m2[4 * c4 + 3]);
            }
        }

        float wd = bm0, pd = 0.f;
        #pragma unroll
        for (int c = 0; c < C_; ++c) {
            float v = fmaxf(m2[c], 0.f);
            m2[c] = v;
            wd = fmaf(v, Wm_s[c], wd);
            pd = fmaf(v, Wx_s[c], pd);
        }
        float w_ = 1.f / (1.f + expf(-wd));
        #pragma unroll
        for (int c = 0; c < C_; ++c) wm_p[c] = fmaf(w_, m2[c], wm_p[c]);
        xa0 = fmaf(pd, xj0, xa0);
        xa1 = fmaf(pd, xj1, xa1);
        xa2 = fmaf(pd, xj2, xa2);
        xa3 = fmaf(pd, xj3, xa3);
    }

    // ---- deterministic fixed-order reduction over j-groups ----
    for (int c0 = 0; c0 < C_; c0 += CH) {
        #pragma unroll
        for (int cc = 0; cc < CH; ++cc) red_s[t][cc] = wm_p[c0 + cc];
        __syncthreads();
        if (t < TI * CH) {
            int li2 = t / CH, cc = t - li2 * CH;
            float s = 0.f;
            #pragma unroll
            for (int g = 0; g < NJG; ++g) s += red_s[g * TI + li2][cc];
            wm_out[(b * P_ + it * TI + li2) * C_ + c0 + cc] = s;
        }
        __syncthreads();
    }
    red_s[t][0] = xa0; red_s[t][1] = xa1; red_s[t][2] = xa2; red_s[t][3] = xa3;
    __syncthreads();
    if (t < TI * 4) {
        int li2 = t >> 2, d = t & 3;
        float s = 0.f;
        #pragma unroll
        for (int g = 0; g < NJG; ++g) s += red_s[g * TI + li2][d];
        xacc_out[(b * P_ + it * TI + li2) * 4 + d] = s;
    }
}

// ---------------- Kernel 3: node MLP + outputs --------------------------
__global__ __launch_bounds__(128) void node_kernel(
    const float* __restrict__ x, const float* __restrict__ h,
    const float* __restrict__ Wh1, const float* __restrict__ bh1,
    const float* __restrict__ Wh2, const float* __restrict__ bh2,
    const float* __restrict__ wm, const float* __restrict__ xacc,
    float* __restrict__ hout, float* __restrict__ xout)
{
    int n = blockIdx.x;
    int t = threadIdx.x;
    __shared__ float g_s[C_];
    __shared__ float h_s[C_], wm_s[C_];
    if (t < C_) { h_s[t] = h[n * C_ + t]; wm_s[t] = wm[n * C_ + t]; }
    __syncthreads();
    if (t < C_) {
        float acc = bh1[t];
        #pragma unroll 8
        for (int k = 0; k < C_; ++k) acc = fmaf(h_s[k], Wh1[k * C_ + t], acc);
        #pragma unroll 8
        for (int k = 0; k < C_; ++k) acc = fmaf(wm_s[k], Wh1[(C_ + k) * C_ + t], acc);
        g_s[t] = fmaxf(acc, 0.f);
    }
    __syncthreads();
    if (t < C_) {
        float acc = bh2[t];
        #pragma unroll 8
        for (int k = 0; k < C_; ++k) acc = fmaf(g_s[k], Wh2[k * C_ + t], acc);
        hout[n * C_ + t] = h_s[t] + acc;
    }
    if (t < 4) {
        xout[n * 4 + t] = x[n * 4 + t] + 0.005f * (xacc[n * 4 + t] * (1.0f / P_));
    }
}

extern "C" void kernel_launch(void* const* d_in, const int* in_sizes, int n_in,
                              void* d_out, int out_size, void* d_ws, size_t ws_size,
                              hipStream_t stream) {
    const float* x   = (const float*)d_in[0];
    const float* h   = (const float*)d_in[1];
    const float* We1 = (const float*)d_in[2];
    const float* be1 = (const float*)d_in[3];
    const float* We2 = (const float*)d_in[4];
    const float* be2 = (const float*)d_in[5];
    const float* Wm  = (const float*)d_in[6];
    const float* bm  = (const float*)d_in[7];
    const float* Wh1 = (const float*)d_in[8];
    const float* bh1 = (const float*)d_in[9];
    const float* Wh2 = (const float*)d_in[10];
    const float* bh2 = (const float*)d_in[11];
    const float* Wx  = (const float*)d_in[12];

    const int NNODE = B_ * P_;               // 8192
    float* A    = (float*)d_ws;              // [8192][72]
    float* Bc   = A  + NNODE * C_;           // [8192][72]
    float* wm   = Bc + NNODE * C_;           // [8192][72]
    float* xacc = wm + NNODE * C_;           // [8192][4]

    float* hout = (float*)d_out;             // [8192][72]
    float* xout = hout + NNODE * C_;         // [8192][4]

    pre_kernel<<<NNODE, 192, 0, stream>>>(h, We1, be1, A, Bc);
    edge_kernel<<<B_ * (P_ / TI), BLK, 0, stream>>>(x, A, Bc, We1, We2, be2,
                                                    Wm, bm, Wx, wm, xacc);
    node_kernel<<<NNODE, 128, 0, stream>>>(x, h, Wh1, bh1, Wh2, bh2,
                                           wm, xacc, hout, xout);
}

// Round 2
// 146.301 us; speedup vs baseline: 4.2822x; 4.2822x over previous
//
#include <hip/hip_runtime.h>
#include <hip/hip_bf16.h>
#include <math.h>

#define B_ 64
#define P_ 128
#define C_ 72
#define MROW 104   // m1 LDS row stride in bf16 units (16B-aligned, 2-way banks)

typedef __attribute__((ext_vector_type(8))) short short8v;
typedef __attribute__((ext_vector_type(4))) float f32x4;

__device__ __forceinline__ float psi_f(float v) {
    return copysignf(log1pf(fabsf(v)), v);
}
// round-to-nearest-even f32 -> bf16 (values are finite)
__device__ __forceinline__ unsigned short f2bf(float f) {
    union { float f; unsigned u; } x; x.f = f;
    unsigned r = x.u + 0x7FFFu + ((x.u >> 16) & 1u);
    return (unsigned short)(r >> 16);
}

// ---------------- Kernel 1: per-node precompute -------------------------
// A[n][c]  = sum_k h[n][k] * We1[k][c]
// Bc[n][c] = sum_k h[n][k] * We1[72+k][c] + be1[c]
__global__ __launch_bounds__(192) void pre_kernel(
    const float* __restrict__ h, const float* __restrict__ We1,
    const float* __restrict__ be1, float* __restrict__ A, float* __restrict__ Bc)
{
    int n = blockIdx.x;
    int t = threadIdx.x;
    __shared__ float h_s[C_];
    if (t < C_) h_s[t] = h[n * C_ + t];
    __syncthreads();
    if (t < C_) {
        float acc = 0.f;
        #pragma unroll 8
        for (int k = 0; k < C_; ++k) acc = fmaf(h_s[k], We1[k * C_ + t], acc);
        A[n * C_ + t] = acc;
    } else if (t < 2 * C_) {
        int c = t - C_;
        float acc = be1[c];
        #pragma unroll 8
        for (int k = 0; k < C_; ++k) acc = fmaf(h_s[k], We1[(C_ + k) * C_ + c], acc);
        Bc[n * C_ + c] = acc;
    }
}

// ---------------- Kernel 2: edge MLP via MFMA ---------------------------
// Block: (b, 16-row i-tile), 4 waves; wave owns 4 i's, loops 8 j-tiles of 16.
// GEMM2 (m1[16x72+pad] @ We2[72x72+pad]) done with mfma_f32_16x16x32_bf16;
// We2 B-fragments held permanently in registers (15 frags).
__global__ __launch_bounds__(256, 2) void edge_kernel(
    const float* __restrict__ x, const float* __restrict__ A,
    const float* __restrict__ Bc, const float* __restrict__ We1,
    const float* __restrict__ We2, const float* __restrict__ be2,
    const float* __restrict__ Wm, const float* __restrict__ bm,
    const float* __restrict__ Wx,
    float* __restrict__ wm_out, float* __restrict__ xacc_out)
{
    __shared__ __align__(16) float A_s[16][76];
    __shared__ __align__(16) float Bc_s[128][76];
    __shared__ __align__(16) float xj_s[128][4];
    __shared__ __align__(16) float w144_s[C_];
    __shared__ __align__(16) float w145_s[C_];
    __shared__ __align__(16) unsigned short m1_s[4][16][MROW]; // per-wave A-tile, bf16

    const int b  = blockIdx.x >> 3;
    const int it = blockIdx.x & 7;
    const int t  = threadIdx.x;
    const int wv = t >> 6;
    const int l  = t & 63;
    const int c16 = l & 15;
    const int g   = l >> 4;

    // ---- stage to LDS ----
    for (int idx = t; idx < 16 * C_; idx += 256) {
        int r = idx / C_, c = idx - r * C_;
        A_s[r][c] = A[(b * P_ + it * 16 + r) * C_ + c];
    }
    for (int idx = t; idx < P_ * C_; idx += 256) {
        int r = idx / C_, c = idx - r * C_;
        Bc_s[r][c] = Bc[(b * P_ + r) * C_ + c];
    }
    for (int idx = t; idx < P_ * 4; idx += 256)
        ((float*)xj_s)[idx] = x[b * P_ * 4 + idx];
    if (t < C_) { w144_s[t] = We1[144 * C_ + t]; w145_s[t] = We1[145 * C_ + t]; }
    __syncthreads();

    // ---- We2 B-fragments in registers: B[k][n], n=nt*16+c16, k=kt*32+g*8+j ----
    short8v Bf[3][5];
    #pragma unroll
    for (int kt = 0; kt < 3; ++kt) {
        #pragma unroll
        for (int nt = 0; nt < 5; ++nt) {
            short8v f;
            #pragma unroll
            for (int jj = 0; jj < 8; ++jj) {
                int k = kt * 32 + g * 8 + jj;
                int n = nt * 16 + c16;
                float w = (k < C_ && n < C_) ? We2[k * C_ + n] : 0.f;
                f[jj] = (short)f2bf(w);
            }
            Bf[kt][nt] = f;
        }
    }

    float be2_l[5], Wm_l[5], Wx_l[5];
    #pragma unroll
    for (int nt = 0; nt < 5; ++nt) {
        int c = nt * 16 + c16;
        bool valid = c < C_;
        be2_l[nt] = valid ? be2[c] : 0.f;
        Wm_l[nt]  = valid ? Wm[c]  : 0.f;
        Wx_l[nt]  = valid ? Wx[c]  : 0.f;
    }
    const float bm0 = bm[0];

    // zero k-pad [72..MROW) of this wave's m1 rows (never rewritten)
    {
        short8v z = {0,0,0,0,0,0,0,0};
        *(short8v*)&m1_s[wv][c16][72 + g * 8] = z;   // g=0..3 -> 72..103
    }

    #pragma unroll 1
    for (int ii = 0; ii < 4; ++ii) {
        const int iloc = wv * 4 + ii;
        const int i = it * 16 + iloc;
        const int node_i = b * P_ + i;
        const f32x4 xi = *(const f32x4*)&xj_s[i][0];

        float wmacc[5] = {0.f, 0.f, 0.f, 0.f, 0.f};
        f32x4 xacc = {0.f, 0.f, 0.f, 0.f};

        #pragma unroll 1
        for (int jt = 0; jt < 8; ++jt) {
            // ---- phase A: m1 -> LDS (lane: edge e=c16, k-range by g) ----
            const int e = c16;
            const int j = jt * 16 + e;
            const f32x4 xjv = *(const f32x4*)&xj_s[j][0];
            float d0 = xi[0] - xjv[0], d1 = xi[1] - xjv[1];
            float d2 = xi[2] - xjv[2], d3 = xi[3] - xjv[3];
            float nn = d0 * d0 - d1 * d1 - d2 * d2 - d3 * d3;
            float pp = xi[0] * xjv[0] - xi[1] * xjv[1] - xi[2] * xjv[2] - xi[3] * xjv[3];
            float n_ = psi_f(nn);
            float p_ = psi_f(pp);

            const int kbeg = g * 16;
            const int kcnt = (g == 3) ? 24 : 16;
            for (int kk = 0; kk < kcnt; kk += 8) {
                const int k = kbeg + kk;
                short8v pk;
                #pragma unroll
                for (int u = 0; u < 8; u += 4) {
                    f32x4 Aq = *(const f32x4*)&A_s[iloc][k + u];
                    f32x4 Bq = *(const f32x4*)&Bc_s[j][k + u];
                    f32x4 w1 = *(const f32x4*)&w144_s[k + u];
                    f32x4 w2 = *(const f32x4*)&w145_s[k + u];
                    #pragma unroll
                    for (int q = 0; q < 4; ++q) {
                        float v = Aq[q] + Bq[q];
                        v = fmaf(n_, w1[q], v);
                        v = fmaf(p_, w2[q], v);
                        v = fmaxf(v, 0.f);
                        pk[u + q] = (short)f2bf(v);
                    }
                }
                *(short8v*)&m1_s[wv][e][k] = pk;
            }

            // ---- phase B: 15 MFMAs (wave-local LDS; compiler orders via lgkmcnt) ----
            f32x4 acc[5] = {};
            #pragma unroll
            for (int kt = 0; kt < 3; ++kt) {
                short8v Af = *(const short8v*)&m1_s[wv][c16][kt * 32 + g * 8];
                #pragma unroll
                for (int nt = 0; nt < 5; ++nt)
                    acc[nt] = __builtin_amdgcn_mfma_f32_16x16x32_bf16(Af, Bf[kt][nt], acc[nt], 0, 0, 0);
            }

            // ---- phase C: epilogue. lane holds m2[row=4g+r][col=nt*16+c16] ----
            float wd[4] = {0.f, 0.f, 0.f, 0.f};
            float pd[4] = {0.f, 0.f, 0.f, 0.f};
            float m2v[5][4];
            #pragma unroll
            for (int nt = 0; nt < 5; ++nt) {
                #pragma unroll
                for (int r = 0; r < 4; ++r) {
                    float v = fmaxf(acc[nt][r] + be2_l[nt], 0.f); // pad cols: 0
                    m2v[nt][r] = v;
                    wd[r] = fmaf(v, Wm_l[nt], wd[r]);
                    pd[r] = fmaf(v, Wx_l[nt], pd[r]);
                }
            }
            // reduce over the 16 column-lanes (fixed butterfly -> deterministic)
            #pragma unroll
            for (int m = 1; m <= 8; m <<= 1) {
                #pragma unroll
                for (int r = 0; r < 4; ++r) {
                    wd[r] += __shfl_xor(wd[r], m, 64);
                    pd[r] += __shfl_xor(pd[r], m, 64);
                }
            }
            #pragma unroll
            for (int r = 0; r < 4; ++r) {
                float w_ = 1.f / (1.f + expf(-(wd[r] + bm0)));
                float pdv = pd[r];
                #pragma unroll
                for (int nt = 0; nt < 5; ++nt)
                    wmacc[nt] = fmaf(w_, m2v[nt][r], wmacc[nt]);
                const f32x4 xr = *(const f32x4*)&xj_s[jt * 16 + 4 * g + r][0];
                #pragma unroll
                for (int q = 0; q < 4; ++q)
                    xacc[q] = fmaf(pdv, xr[q], xacc[q]);
            }
        } // jt

        // ---- finalize i: reduce across the 4 row-groups ----
        #pragma unroll
        for (int m = 16; m <= 32; m <<= 1) {
            #pragma unroll
            for (int nt = 0; nt < 5; ++nt) wmacc[nt] += __shfl_xor(wmacc[nt], m, 64);
            #pragma unroll
            for (int q = 0; q < 4; ++q)   xacc[q]   += __shfl_xor(xacc[q], m, 64);
        }
        if (l < 16) {
            #pragma unroll
            for (int nt = 0; nt < 5; ++nt) {
                int c = nt * 16 + l;
                if (c < C_) wm_out[node_i * C_ + c] = wmacc[nt];
            }
        }
        if (l == 0)
            *(f32x4*)&xacc_out[node_i * 4] = xacc;
    } // ii
}

// ---------------- Kernel 3: node MLP + outputs --------------------------
__global__ __launch_bounds__(128) void node_kernel(
    const float* __restrict__ x, const float* __restrict__ h,
    const float* __restrict__ Wh1, const float* __restrict__ bh1,
    const float* __restrict__ Wh2, const float* __restrict__ bh2,
    const float* __restrict__ wm, const float* __restrict__ xacc,
    float* __restrict__ hout, float* __restrict__ xout)
{
    int n = blockIdx.x;
    int t = threadIdx.x;
    __shared__ float g_s[C_];
    __shared__ float h_s[C_], wm_s[C_];
    if (t < C_) { h_s[t] = h[n * C_ + t]; wm_s[t] = wm[n * C_ + t]; }
    __syncthreads();
    if (t < C_) {
        float acc = bh1[t];
        #pragma unroll 8
        for (int k = 0; k < C_; ++k) acc = fmaf(h_s[k], Wh1[k * C_ + t], acc);
        #pragma unroll 8
        for (int k = 0; k < C_; ++k) acc = fmaf(wm_s[k], Wh1[(C_ + k) * C_ + t], acc);
        g_s[t] = fmaxf(acc, 0.f);
    }
    __syncthreads();
    if (t < C_) {
        float acc = bh2[t];
        #pragma unroll 8
        for (int k = 0; k < C_; ++k) acc = fmaf(g_s[k], Wh2[k * C_ + t], acc);
        hout[n * C_ + t] = h_s[t] + acc;
    }
    if (t < 4) {
        xout[n * 4 + t] = x[n * 4 + t] + 0.005f * (xacc[n * 4 + t] * (1.0f / P_));
    }
}

extern "C" void kernel_launch(void* const* d_in, const int* in_sizes, int n_in,
                              void* d_out, int out_size, void* d_ws, size_t ws_size,
                              hipStream_t stream) {
    const float* x   = (const float*)d_in[0];
    const float* h   = (const float*)d_in[1];
    const float* We1 = (const float*)d_in[2];
    const float* be1 = (const float*)d_in[3];
    const float* We2 = (const float*)d_in[4];
    const float* be2 = (const float*)d_in[5];
    const float* Wm  = (const float*)d_in[6];
    const float* bm  = (const float*)d_in[7];
    const float* Wh1 = (const float*)d_in[8];
    const float* bh1 = (const float*)d_in[9];
    const float* Wh2 = (const float*)d_in[10];
    const float* bh2 = (const float*)d_in[11];
    const float* Wx  = (const float*)d_in[12];

    const int NNODE = B_ * P_;               // 8192
    float* A    = (float*)d_ws;              // [8192][72]
    float* Bc   = A  + NNODE * C_;           // [8192][72]
    float* wm   = Bc + NNODE * C_;           // [8192][72]
    float* xacc = wm + NNODE * C_;           // [8192][4]

    float* hout = (float*)d_out;             // [8192][72]
    float* xout = hout + NNODE * C_;         // [8192][4]

    pre_kernel<<<NNODE, 192, 0, stream>>>(h, We1, be1, A, Bc);
    edge_kernel<<<B_ * 8, 256, 0, stream>>>(x, A, Bc, We1, We2, be2,
                                            Wm, bm, Wx, wm, xacc);
    node_kernel<<<NNODE, 128, 0, stream>>>(x, h, Wh1, bh1, Wh2, bh2,
                                           wm, xacc, hout, xout);
}